// Round 3
// baseline (306.074 us; speedup 1.0000x reference)
//
#include <hip/hip_runtime.h>

// Problem constants (fixed by reference setup_inputs)
#define B_    4
#define C_    128
#define H_    64
#define W_    64
#define CO_   128
#define K_    9
#define DG_   2
#define HW_   4096      // H*W == Ho*Wo
#define CK_   1152      // C_*K_
#define NKT_  36        // CK_/32 K-tiles of 32

typedef __attribute__((ext_vector_type(8))) short  short8;
typedef __attribute__((ext_vector_type(4))) float  floatx4;

// MFMA-native staging buffers (static __device__; fully rewritten every launch)
__device__ __align__(16) unsigned short g_wbf[NKT_ * CO_ * 32];       // [kt][co][32k] bf16, 294 KB
__device__ __align__(16) unsigned short g_col[B_ * NKT_ * HW_ * 32];  // [b][kt][pix][32k] bf16, 37.7 MB
__device__ __align__(16) int4   g_idx[B_ * DG_ * K_ * HW_];           // 4.7 MB
__device__ __align__(16) float4 g_wt [B_ * DG_ * K_ * HW_];           // 4.7 MB

__device__ __forceinline__ unsigned short f32_to_bf16(float f) {
    unsigned int u = __float_as_uint(f);
    u += 0x7FFFu + ((u >> 16) & 1u);           // round-to-nearest-even
    return (unsigned short)(u >> 16);
}

// ---- Kernel 1: weight -> bf16 [kt][co][32] ----
__global__ void prep_w_kernel(const float* __restrict__ w) {
    int lin = blockIdx.x * 256 + threadIdx.x;   // 147456 total
    int kt = lin >> 12;                         // /(128*32)
    int co = (lin >> 5) & 127;
    int j  = lin & 31;
    g_wbf[lin] = f32_to_bf16(w[co * CK_ + kt * 32 + j]);
}

// ---- Kernel 2: bilinear descriptors for all (b,g,k,pix) ----
__global__ __launch_bounds__(256) void desc_kernel(
    const float* __restrict__ offset, const float* __restrict__ mask)
{
    const int lin = blockIdx.x * 256 + threadIdx.x;   // 294912 total
    const int pix = lin & (HW_ - 1);
    const int bgk = lin >> 12;                        // (b*2+g)*9 + k
    const int k   = bgk % 9;
    const int bg  = bgk / 9;
    const int ho = pix >> 6;
    const int wo = pix & 63;
    const int ky = k / 3;
    const int kx = k - ky * 3;

    const float py = offset[(size_t)(bg * 18 + k * 2)     * HW_ + pix] + (float)(ho - 1 + ky);
    const float px = offset[(size_t)(bg * 18 + k * 2 + 1) * HW_ + pix] + (float)(wo - 1 + kx);
    const float m  = mask  [(size_t)(bg * 9 + k)          * HW_ + pix];

    const float y0f = floorf(py);
    const float x0f = floorf(px);
    const float ly = py - y0f;
    const float lx = px - x0f;
    const int y0 = (int)y0f;
    const int x0 = (int)x0f;

    const float w00 = (1.0f - ly) * (1.0f - lx) * m;
    const float w01 = (1.0f - ly) * lx * m;
    const float w10 = ly * (1.0f - lx) * m;
    const float w11 = ly * lx * m;

    int   idx[4];
    float wt[4];
    const int ys[4] = { y0, y0, y0 + 1, y0 + 1 };
    const int xs[4] = { x0, x0 + 1, x0, x0 + 1 };
    const float ws[4] = { w00, w01, w10, w11 };
#pragma unroll
    for (int c2 = 0; c2 < 4; ++c2) {
        const bool v = (ys[c2] >= 0) & (ys[c2] < H_) & (xs[c2] >= 0) & (xs[c2] < W_);
        idx[c2] = v ? (ys[c2] * W_ + xs[c2]) : 0;
        wt[c2]  = v ? ws[c2] : 0.0f;
    }
    g_idx[lin] = make_int4(idx[0], idx[1], idx[2], idx[3]);
    g_wt [lin] = make_float4(wt[0], wt[1], wt[2], wt[3]);
}

// ---- Kernel 3 (hot): build col[b][kt][pix][32k] bf16 ----
// Thread = (pixel, j-octet). Three unrolled passes (desc loads -> gathers ->
// combine) to force deep MLP; block stores are fully contiguous.
__global__ __launch_bounds__(256) void col_kernel(const float* __restrict__ x)
{
    const int bid = blockIdx.x;                 // 9216 = 4b * 36kt * 64ptiles
    const int b   = bid / 2304;
    const int rem = bid - b * 2304;
    const int kt  = rem >> 6;
    const int pt  = rem & 63;
    const int tid = threadIdx.x;
    const int jo   = tid & 3;                   // j-octet
    const int pixl = tid >> 2;                  // 0..63
    const int pix  = pt * 64 + pixl;

    const float* __restrict__ xb = x + (size_t)b * C_ * HW_;

    int4   di[8];
    float4 dw[8];
    int    cc[8];
#pragma unroll
    for (int i = 0; i < 8; ++i) {
        const int ck = kt * 32 + jo * 8 + i;
        const int c  = ck / 9;
        const int k  = ck - 9 * c;
        const int g  = c >> 6;
        const int dix = ((b * DG_ + g) * 9 + k) * HW_ + pix;
        di[i] = g_idx[dix];
        dw[i] = g_wt[dix];
        cc[i] = c;
    }

    float4 gv[8];
#pragma unroll
    for (int i = 0; i < 8; ++i) {
        const float* __restrict__ xc = xb + (size_t)cc[i] * HW_;
        gv[i] = make_float4(xc[di[i].x], xc[di[i].y], xc[di[i].z], xc[di[i].w]);
    }

    short8 sv;
#pragma unroll
    for (int i = 0; i < 8; ++i) {
        const float v = dw[i].x * gv[i].x + dw[i].y * gv[i].y
                      + dw[i].z * gv[i].z + dw[i].w * gv[i].w;
        sv[i] = (short)f32_to_bf16(v);
    }
    *(short8*)&g_col[((size_t)(b * NKT_ + kt) * HW_ + pix) * 32 + jo * 8] = sv;
}

// ---- Kernel 4: GEMM out[b][co][pix] = W @ col, zero LDS, frags from L2 ----
__global__ __launch_bounds__(256) void gemm_kernel(
    const float* __restrict__ bias, float* __restrict__ out)
{
    const int bid = blockIdx.x;                 // 256 = 4b * 64 ntiles
    const int b   = bid >> 6;
    const int pb  = (bid & 63) * 64;
    const int tid = threadIdx.x;
    const int wv   = tid >> 6;                  // wave -> 16-pixel n-slice
    const int lane = tid & 63;
    const int l15  = lane & 15;
    const int quad = lane >> 4;
    const int pix  = pb + wv * 16 + l15;

    const unsigned short* __restrict__ bp =
        g_col + ((size_t)(b * NKT_) * HW_ + pix) * 32 + quad * 8;   // += 131072/kt
    const unsigned short* __restrict__ ap =
        g_wbf + (size_t)l15 * 32 + quad * 8;    // + kt*4096 + mt*512

    floatx4 acc[8];
#pragma unroll
    for (int mt = 0; mt < 8; ++mt) acc[mt] = floatx4{0.f, 0.f, 0.f, 0.f};

    short8 af[2][8], bf[2];
    bf[0] = *(const short8*)bp;
#pragma unroll
    for (int mt = 0; mt < 8; ++mt)
        af[0][mt] = *(const short8*)(ap + mt * 512);

#pragma unroll 2
    for (int kt = 0; kt < NKT_; ++kt) {
        const int cur = kt & 1;
        const int nxt = cur ^ 1;
        if (kt < NKT_ - 1) {
            bf[nxt] = *(const short8*)(bp + (size_t)(kt + 1) * 131072);
            const unsigned short* an = ap + (kt + 1) * 4096;
#pragma unroll
            for (int mt = 0; mt < 8; ++mt)
                af[nxt][mt] = *(const short8*)(an + mt * 512);
        }
#pragma unroll
        for (int mt = 0; mt < 8; ++mt)
            acc[mt] = __builtin_amdgcn_mfma_f32_16x16x32_bf16(af[cur][mt], bf[cur], acc[mt], 0, 0, 0);
    }

    // C/D layout: col = l15 (pixel), row = quad*4 + r (co within 16-tile)
#pragma unroll
    for (int mt = 0; mt < 8; ++mt) {
#pragma unroll
        for (int r = 0; r < 4; ++r) {
            const int co = mt * 16 + quad * 4 + r;
            out[((size_t)(b * CO_ + co) << 12) + pix] = acc[mt][r] + bias[co];
        }
    }
}

extern "C" void kernel_launch(void* const* d_in, const int* in_sizes, int n_in,
                              void* d_out, int out_size, void* d_ws, size_t ws_size,
                              hipStream_t stream) {
    const float* x      = (const float*)d_in[0];
    const float* offset = (const float*)d_in[1];
    const float* mask   = (const float*)d_in[2];
    const float* weight = (const float*)d_in[3];
    const float* bias   = (const float*)d_in[4];
    float* out = (float*)d_out;

    hipLaunchKernelGGL(prep_w_kernel, dim3(NKT_ * CO_ * 32 / 256), dim3(256), 0, stream, weight);
    hipLaunchKernelGGL(desc_kernel, dim3(B_ * DG_ * K_ * HW_ / 256), dim3(256), 0, stream, offset, mask);
    hipLaunchKernelGGL(col_kernel, dim3(B_ * NKT_ * (HW_ / 64)), dim3(256), 0, stream, x);
    hipLaunchKernelGGL(gemm_kernel, dim3(B_ * (HW_ / 64)), dim3(256), 0, stream, bias, out);
}

// Round 4
// 142.383 us; speedup vs baseline: 2.1496x; 2.1496x over previous
//
#include <hip/hip_runtime.h>
#include <hip/hip_fp16.h>

// Problem constants (fixed by reference setup_inputs)
#define B_    4
#define C_    128
#define H_    64
#define W_    64
#define CO_   128
#define K_    9
#define DG_   2
#define HW_   4096
#define CK_   1152
#define NKT_  36        // CK_/32

typedef __attribute__((ext_vector_type(8))) short  short8;
typedef __attribute__((ext_vector_type(4))) float  floatx4;
typedef float f2v __attribute__((ext_vector_type(2), aligned(4)));   // 4B-aligned float2 gather
typedef short s8v __attribute__((ext_vector_type(8), aligned(8)));
typedef short s4v __attribute__((ext_vector_type(4), aligned(8)));

// Static staging buffers, fully rewritten every launch.
__device__ __align__(16) unsigned short g_wbf[NKT_ * CO_ * 32];        // [kt][co][32k] bf16
__device__ __align__(16) unsigned short g_col[(size_t)B_ * HW_ * CK_]; // [b][pix][ck] bf16, 37.7 MB
__device__ __align__(16) int4           g_desc[B_ * DG_ * K_ * HW_];   // {base, h2(w00,w01), h2(w10,w11), 0}

__device__ __forceinline__ unsigned short f32_to_bf16(float f) {
    unsigned int u = __float_as_uint(f);
    u += 0x7FFFu + ((u >> 16) & 1u);           // round-to-nearest-even
    return (unsigned short)(u >> 16);
}

// ---- Kernel 1: weight->bf16 [kt][co][32]  +  bilinear descriptors (merged) ----
__global__ __launch_bounds__(256) void prep_kernel(
    const float* __restrict__ w,
    const float* __restrict__ offset,
    const float* __restrict__ mask)
{
    const int bid = blockIdx.x;
    if (bid < 576) {
        // weights: 147456 elements
        const int lin = bid * 256 + threadIdx.x;
        const int kt = lin >> 12;
        const int co = (lin >> 5) & 127;
        const int j  = lin & 31;
        g_wbf[lin] = f32_to_bf16(w[co * CK_ + kt * 32 + j]);
    } else {
        // descriptors: 294912 = 72 bgk * 4096 pix
        const int lin = (bid - 576) * 256 + threadIdx.x;
        const int pix = lin & (HW_ - 1);
        const int bgk = lin >> 12;             // (b*2+g)*9 + k
        const int k   = bgk % 9;
        const int bg  = bgk / 9;
        const int ho = pix >> 6;
        const int wo = pix & 63;
        const int ky = k / 3;
        const int kx = k - 3 * ky;

        const float py = offset[(size_t)(bg * 18 + 2 * k)     * HW_ + pix] + (float)(ho - 1 + ky);
        const float px = offset[(size_t)(bg * 18 + 2 * k + 1) * HW_ + pix] + (float)(wo - 1 + kx);
        const float m  = mask  [(size_t)(bg * 9 + k)          * HW_ + pix];

        const float y0f = floorf(py);
        const float x0f = floorf(px);
        const float ly = py - y0f;
        const float lx = px - x0f;
        const int y0 = (int)y0f;
        const int x0 = (int)x0f;

        // clamped 2x2 load window (rows yc,yc+1; cols xc,xc+1) + folded edge weights
        const bool yin = (y0 >= 0) & (y0 <= H_ - 2);
        const float er0 = yin ? (1.0f - ly) : ((y0 == -1)     ? ly          : 0.0f);
        const float er1 = yin ? ly          : ((y0 == H_ - 1) ? (1.0f - ly) : 0.0f);
        const bool xin = (x0 >= 0) & (x0 <= W_ - 2);
        const float ec0 = xin ? (1.0f - lx) : ((x0 == -1)     ? lx          : 0.0f);
        const float ec1 = xin ? lx          : ((x0 == W_ - 1) ? (1.0f - lx) : 0.0f);
        const int yc = min(max(y0, 0), H_ - 2);
        const int xc = min(max(x0, 0), W_ - 2);

        const __half2 wlo = __floats2half2_rn(m * er0 * ec0, m * er0 * ec1);
        const __half2 whi = __floats2half2_rn(m * er1 * ec0, m * er1 * ec1);
        int4 d;
        d.x = yc * W_ + xc;
        d.y = __builtin_bit_cast(int, wlo);
        d.z = __builtin_bit_cast(int, whi);
        d.w = 0;
        g_desc[lin] = d;
    }
}

// ---- Kernel 2 (hot): col[b][pix][ck] bf16. Block = (b, 4 channels, 256 pix). ----
// Thread = one pixel: preload 9 descriptors (its deform group), sample 4 ch x 9 k.
// A wave's gather = 64 consecutive pixels of ONE channel plane -> coherent addresses.
__global__ __launch_bounds__(256, 4) void col_kernel(const float* __restrict__ x)
{
    const int bid = blockIdx.x;            // 2048 = 4b * 32cg * 16pt
    const int b   = bid >> 9;
    const int rem = bid & 511;
    const int cg  = rem >> 4;              // channel quad 0..31
    const int pt  = rem & 15;
    const int c0  = cg * 4;
    const int g   = c0 >> 6;               // whole block in one deform group (4 | 64)
    const int pix = pt * 256 + threadIdx.x;

    const int4* __restrict__ dbase = g_desc + ((size_t)(b * DG_ + g) * 9) * HW_ + pix;
    int4 d[9];
#pragma unroll
    for (int k = 0; k < 9; ++k) d[k] = dbase[(size_t)k * HW_];

    const float* __restrict__ xb = x + (size_t)(b * C_ + c0) * HW_;
    short sv[36];
#pragma unroll
    for (int ci = 0; ci < 4; ++ci) {
        const float* __restrict__ xc = xb + ci * HW_;
#pragma unroll
        for (int k = 0; k < 9; ++k) {
            const int4 dd = d[k];
            const f2v lo = *(const f2v*)(xc + dd.x);
            const f2v hi = *(const f2v*)(xc + dd.x + W_);
            const float2 wl = __half22float2(__builtin_bit_cast(__half2, dd.y));
            const float2 wh = __half22float2(__builtin_bit_cast(__half2, dd.z));
            const float v = wl.x * lo.x + wl.y * lo.y + wh.x * hi.x + wh.y * hi.y;
            sv[ci * 9 + k] = (short)f32_to_bf16(v);
        }
    }

    // 72B contiguous store per thread (8B-aligned: offset = 72*cg within a 2304B row)
    unsigned short* gout = g_col + ((size_t)(b * HW_) + pix) * CK_ + c0 * 9;
#pragma unroll
    for (int q = 0; q < 4; ++q) {
        s8v t;
#pragma unroll
        for (int i = 0; i < 8; ++i) t[i] = sv[q * 8 + i];
        *(s8v*)(gout + q * 8) = t;
    }
    s4v t2;
#pragma unroll
    for (int i = 0; i < 4; ++i) t2[i] = sv[32 + i];
    *(s4v*)(gout + 32) = t2;
}

// ---- Kernel 3: GEMM. 1024 blocks (4/CU): b, 16-pix n-tile, all 128 co. ----
// Col slab staged via LDS (transposes [pix][ck] rows into bank-friendly tile);
// A-frags streamed from L2-hot g_wbf with depth-1 prefetch.
#define BSTR_ 1160   // LDS row stride in shorts (1152+8 -> 2-way banks only)
__global__ __launch_bounds__(256) void gemm_kernel(
    const float* __restrict__ bias, float* __restrict__ out)
{
    const int bid  = blockIdx.x;           // 1024 = 4b * 256 ptiles
    const int b    = bid >> 8;
    const int pixb = (bid & 255) * 16;
    const int tid  = threadIdx.x;

    __shared__ __align__(16) unsigned short s_b[16 * BSTR_];   // 37120 B

    {   // stage 16 pix x 1152 ck (9 x 16B chunks per thread, coalesced)
        const unsigned short* __restrict__ src = g_col + (size_t)(b * HW_ + pixb) * CK_;
#pragma unroll
        for (int i = 0; i < 9; ++i) {
            const int lin = tid + i * 256;          // 0..2303
            const int pl  = lin / 144;              // 144 chunks per pixel row
            const int of  = lin - pl * 144;
            const short8 v = *(const short8*)(src + (size_t)pl * CK_ + of * 8);
            *(short8*)&s_b[pl * BSTR_ + of * 8] = v;
        }
    }
    __syncthreads();

    const int wv   = tid >> 6;             // wave -> co range [wv*32, wv*32+32)
    const int lane = tid & 63;
    const int l15  = lane & 15;
    const int quad = lane >> 4;

    const unsigned short* __restrict__ ap0 = g_wbf + (size_t)(wv * 32 + l15) * 32 + quad * 8;
    const unsigned short* __restrict__ ap1 = ap0 + 16 * 32;
    const unsigned short* bp = s_b + l15 * BSTR_ + quad * 8;

    floatx4 acc0 = {0.f, 0.f, 0.f, 0.f};
    floatx4 acc1 = {0.f, 0.f, 0.f, 0.f};

    short8 a0c = *(const short8*)ap0;
    short8 a1c = *(const short8*)ap1;
    short8 bc  = *(const short8*)bp;

    for (int kt = 0; kt < NKT_; ++kt) {
        const int ktn = (kt + 1 < NKT_) ? kt + 1 : NKT_ - 1;
        const short8 a0n = *(const short8*)(ap0 + (size_t)ktn * 4096);
        const short8 a1n = *(const short8*)(ap1 + (size_t)ktn * 4096);
        const short8 bn  = *(const short8*)(bp + ktn * 32);
        acc0 = __builtin_amdgcn_mfma_f32_16x16x32_bf16(a0c, bc, acc0, 0, 0, 0);
        acc1 = __builtin_amdgcn_mfma_f32_16x16x32_bf16(a1c, bc, acc1, 0, 0, 0);
        a0c = a0n; a1c = a1n; bc = bn;
    }

    // C/D layout: col = l15 (pixel), row = quad*4 + r (co within 16-tile)
#pragma unroll
    for (int t = 0; t < 2; ++t) {
        const floatx4 a = t ? acc1 : acc0;
        const int cob = wv * 32 + t * 16 + quad * 4;
#pragma unroll
        for (int r = 0; r < 4; ++r) {
            const int co = cob + r;
            out[((size_t)(b * CO_ + co) << 12) + pixb + l15] = a[r] + bias[co];
        }
    }
}

extern "C" void kernel_launch(void* const* d_in, const int* in_sizes, int n_in,
                              void* d_out, int out_size, void* d_ws, size_t ws_size,
                              hipStream_t stream) {
    const float* x      = (const float*)d_in[0];
    const float* offset = (const float*)d_in[1];
    const float* mask   = (const float*)d_in[2];
    const float* weight = (const float*)d_in[3];
    const float* bias   = (const float*)d_in[4];
    float* out = (float*)d_out;

    hipLaunchKernelGGL(prep_kernel, dim3(576 + 1152), dim3(256), 0, stream, weight, offset, mask);
    hipLaunchKernelGGL(col_kernel, dim3(2048), dim3(256), 0, stream, x);
    hipLaunchKernelGGL(gemm_kernel, dim3(1024), dim3(256), 0, stream, bias, out);
}

// Round 5
// 130.779 us; speedup vs baseline: 2.3404x; 1.0887x over previous
//
#include <hip/hip_runtime.h>
#include <hip/hip_fp16.h>

// Problem constants (fixed by reference setup_inputs)
#define B_    4
#define C_    128
#define H_    64
#define W_    64
#define CO_   128
#define K_    9
#define DG_   2
#define HW_   4096
#define CK_   1152
#define NKT_  36        // CK_/32
#define NPAIR_ 576      // CK_/2
#define PSTR_ 68        // padded LDS plane row stride (floats): bank-rotating, 16B-aligned
#define PLSZ_ 4352      // 64*PSTR_ floats per plane

typedef __attribute__((ext_vector_type(8))) short  short8;
typedef __attribute__((ext_vector_type(4))) float  floatx4;
typedef float f2v __attribute__((ext_vector_type(2), aligned(4)));   // dword-aligned pair (ds_read2_b32)

// Static staging buffers, fully rewritten every launch.
__device__ __align__(16) unsigned short g_wbf[NKT_ * CO_ * 32];        // [kt][co][32k] bf16, ck=c*9+k
__device__ __align__(16) unsigned int   g_colu[(size_t)B_ * NPAIR_ * HW_]; // pair-interleaved col: [b][ck/2][pix]{lo=ck even}
__device__ __align__(16) int4           g_desc[B_ * DG_ * K_ * HW_];   // {padded base, h2(w00,w01), h2(w10,w11), 0}

__device__ __forceinline__ unsigned short f32_to_bf16(float f) {
    unsigned int u = __float_as_uint(f);
    u += 0x7FFFu + ((u >> 16) & 1u);           // round-to-nearest-even
    return (unsigned short)(u >> 16);
}
__device__ __forceinline__ unsigned int pack_bf16x2(float a, float b) {
    return (unsigned int)f32_to_bf16(a) | ((unsigned int)f32_to_bf16(b) << 16);
}

// ---- Kernel 1: weight->bf16 [kt][co][32]  +  bilinear descriptors (merged) ----
__global__ __launch_bounds__(256) void prep_kernel(
    const float* __restrict__ w,
    const float* __restrict__ offset,
    const float* __restrict__ mask)
{
    const int bid = blockIdx.x;
    if (bid < 576) {
        // weights: 147456 elements
        const int lin = bid * 256 + threadIdx.x;
        const int kt = lin >> 12;
        const int co = (lin >> 5) & 127;
        const int j  = lin & 31;
        g_wbf[lin] = f32_to_bf16(w[co * CK_ + kt * 32 + j]);
    } else {
        // descriptors: 294912 = 72 bgk * 4096 pix
        const int lin = (bid - 576) * 256 + threadIdx.x;
        const int pix = lin & (HW_ - 1);
        const int bgk = lin >> 12;             // (b*2+g)*9 + k
        const int k   = bgk % 9;
        const int bg  = bgk / 9;
        const int ho = pix >> 6;
        const int wo = pix & 63;
        const int ky = k / 3;
        const int kx = k - 3 * ky;

        const float py = offset[(size_t)(bg * 18 + 2 * k)     * HW_ + pix] + (float)(ho - 1 + ky);
        const float px = offset[(size_t)(bg * 18 + 2 * k + 1) * HW_ + pix] + (float)(wo - 1 + kx);
        const float m  = mask  [(size_t)(bg * 9 + k)          * HW_ + pix];

        const float y0f = floorf(py);
        const float x0f = floorf(px);
        const float ly = py - y0f;
        const float lx = px - x0f;
        const int y0 = (int)y0f;
        const int x0 = (int)x0f;

        // clamped 2x2 load window + folded edge weights
        const bool yin = (y0 >= 0) & (y0 <= H_ - 2);
        const float er0 = yin ? (1.0f - ly) : ((y0 == -1)     ? ly          : 0.0f);
        const float er1 = yin ? ly          : ((y0 == H_ - 1) ? (1.0f - ly) : 0.0f);
        const bool xin = (x0 >= 0) & (x0 <= W_ - 2);
        const float ec0 = xin ? (1.0f - lx) : ((x0 == -1)     ? lx          : 0.0f);
        const float ec1 = xin ? lx          : ((x0 == W_ - 1) ? (1.0f - lx) : 0.0f);
        const int yc = min(max(y0, 0), H_ - 2);
        const int xc = min(max(x0, 0), W_ - 2);

        const __half2 wlo = __floats2half2_rn(m * er0 * ec0, m * er0 * ec1);
        const __half2 whi = __floats2half2_rn(m * er1 * ec0, m * er1 * ec1);
        int4 d;
        d.x = yc * PSTR_ + xc;                 // PADDED-plane base for LDS sampling
        d.y = __builtin_bit_cast(int, wlo);
        d.z = __builtin_bit_cast(int, whi);
        d.w = 0;
        g_desc[lin] = d;
    }
}

// ---- Kernel 2 (hot): col from LDS-staged planes. Block = (b, channel-pair). ----
// 256 blocks (1/CU) x 1024 threads (16 waves). Whole 2 planes in LDS (padded),
// every bilinear tap = ds_read2_b32; clamped bases are always in-plane.
__global__ __launch_bounds__(1024, 4) void col_kernel(const float* __restrict__ x)
{
    const int bid = blockIdx.x;            // 256 = 4b * 64 channel-pairs
    const int b   = bid >> 6;
    const int cp  = bid & 63;
    const int c0  = cp * 2;
    const int g   = c0 >> 6;
    const int t   = threadIdx.x;

    __shared__ __align__(16) float s_x[2 * PLSZ_];   // 34816 B

    {   // stage 2 planes, padded rows (8 floats per thread, 16B-aligned in LDS)
        const int ci = t >> 9;
        const int q  = t & 511;
        const float* __restrict__ src = x + (size_t)(b * C_ + c0 + ci) * HW_ + q * 8;
        const float4 v0 = *(const float4*)src;
        const float4 v1 = *(const float4*)(src + 4);
        float* dst = s_x + ci * PLSZ_ + (q >> 3) * PSTR_ + (q & 7) * 8;
        *(float4*)dst = v0;
        *(float4*)(dst + 4) = v1;
    }
    __syncthreads();

    const int4* __restrict__ descb = g_desc + (size_t)((b * DG_ + g) * 9) * HW_;
    unsigned int* __restrict__ outb = g_colu + (size_t)(b * NPAIR_ + cp * 9) * HW_;

#pragma unroll
    for (int ps = 0; ps < 4; ++ps) {
        const int pix = ps * 1024 + t;
        int4 d[9];
#pragma unroll
        for (int k = 0; k < 9; ++k) d[k] = descb[(size_t)k * HW_ + pix];

        float v[18];
#pragma unroll
        for (int k = 0; k < 9; ++k) {
            const float2 wl = __half22float2(__builtin_bit_cast(__half2, d[k].y));
            const float2 wh = __half22float2(__builtin_bit_cast(__half2, d[k].z));
#pragma unroll
            for (int ci = 0; ci < 2; ++ci) {
                const float* p = s_x + ci * PLSZ_ + d[k].x;
                const f2v lo = *(const f2v*)p;
                const f2v hi = *(const f2v*)(p + PSTR_);
                v[ci * 9 + k] = wl.x * lo.x + wl.y * lo.y + wh.x * hi.x + wh.y * hi.y;
            }
        }
        // local ck = ci*9+k; global ck = c0*9 + local (c0 even -> pair-aligned).
        // pair j holds (local 2j, 2j+1) -> dword {lo=even ck, hi=odd ck}
#pragma unroll
        for (int j = 0; j < 9; ++j)
            outb[(size_t)j * HW_ + pix] = pack_bf16x2(v[2 * j], v[2 * j + 1]);
    }
}

// ---- Kernel 3: GEMM, zero LDS. 1024 blocks x 512 thr (8 waves co-split-16). ----
// B-frags: 4 coalesced b32 loads from pair-interleaved col (k-octet = 4 pairs).
// A-frags: contiguous b128 from L2-hot g_wbf. Depth-1 prefetch, 32 waves/CU.
__global__ __launch_bounds__(512) void gemm_kernel(
    const float* __restrict__ bias, float* __restrict__ out)
{
    const int bid  = blockIdx.x;           // 1024 = 4b * 256 ptiles(16)
    const int b    = bid >> 8;
    const int pixb = (bid & 255) * 16;
    const int t    = threadIdx.x;
    const int wv   = t >> 6;               // 0..7 -> co0 = wv*16
    const int lane = t & 63;
    const int l15  = lane & 15;
    const int quad = lane >> 4;
    const int co0  = wv * 16;
    const int pix  = pixb + l15;

    // A: lane holds w[co0+l15][kt*32 + quad*8 .. +8)
    const unsigned short* __restrict__ ap = g_wbf + (size_t)(co0 + l15) * 32 + quad * 8;
    // B: lane needs col[kt*32+quad*8+j][pix] -> pairs kt*16+quad*4+p
    const unsigned int* __restrict__ bp = g_colu + (size_t)(b * NPAIR_ + quad * 4) * HW_ + pix;

    floatx4 acc = {0.f, 0.f, 0.f, 0.f};

    short8 a_c = *(const short8*)ap;
    uint4 w;
    w.x = bp[0]; w.y = bp[HW_]; w.z = bp[2 * HW_]; w.w = bp[3 * HW_];
    short8 b_c = __builtin_bit_cast(short8, w);

#pragma unroll 4
    for (int kt = 0; kt < NKT_; ++kt) {
        short8 a_n = a_c, b_n = b_c;
        if (kt < NKT_ - 1) {
            a_n = *(const short8*)(ap + (size_t)(kt + 1) * 4096);
            const unsigned int* bq = bp + (size_t)(kt + 1) * 16 * HW_;
            uint4 u;
            u.x = bq[0]; u.y = bq[HW_]; u.z = bq[2 * HW_]; u.w = bq[3 * HW_];
            b_n = __builtin_bit_cast(short8, u);
        }
        acc = __builtin_amdgcn_mfma_f32_16x16x32_bf16(a_c, b_c, acc, 0, 0, 0);
        a_c = a_n;
        b_c = b_n;
    }

    // C/D: col = l15 (pixel), row = quad*4 + r (co within 16-tile)
#pragma unroll
    for (int r = 0; r < 4; ++r) {
        const int co = co0 + quad * 4 + r;
        out[((size_t)(b * CO_ + co) << 12) + pix] = acc[r] + bias[co];
    }
}

extern "C" void kernel_launch(void* const* d_in, const int* in_sizes, int n_in,
                              void* d_out, int out_size, void* d_ws, size_t ws_size,
                              hipStream_t stream) {
    const float* x      = (const float*)d_in[0];
    const float* offset = (const float*)d_in[1];
    const float* mask   = (const float*)d_in[2];
    const float* weight = (const float*)d_in[3];
    const float* bias   = (const float*)d_in[4];
    float* out = (float*)d_out;

    hipLaunchKernelGGL(prep_kernel, dim3(576 + 1152), dim3(256), 0, stream, weight, offset, mask);
    hipLaunchKernelGGL(col_kernel, dim3(B_ * 64), dim3(1024), 0, stream, x);
    hipLaunchKernelGGL(gemm_kernel, dim3(B_ * 256), dim3(512), 0, stream, bias, out);
}

// Round 6
// 107.012 us; speedup vs baseline: 2.8602x; 1.2221x over previous
//
#include <hip/hip_runtime.h>
#include <hip/hip_fp16.h>

// Problem constants (fixed by reference setup_inputs)
#define B_    4
#define C_    128
#define H_    64
#define W_    64
#define CO_   128
#define K_    9
#define DG_   2
#define HW_   4096
#define CK_   1152
#define NKT_  36        // CK_/32
#define NPAIR_ 576      // CK_/2
#define PSTR_ 68        // padded LDS plane row stride (floats) in col kernel
#define PLSZ_ 4352      // 64*PSTR_ floats per plane
#define LSTR_ 580       // gemm LDS row stride in uints (576+4 -> 2-way banks only)

typedef __attribute__((ext_vector_type(8))) short  short8;
typedef __attribute__((ext_vector_type(4))) float  floatx4;
typedef float f2v __attribute__((ext_vector_type(2), aligned(4)));   // dword-aligned pair (ds_read2_b32)

// Static staging buffers, fully rewritten every launch.
// A in MFMA-fragment order: [kt][mt(co16)][lane][8k], lane=quad*16+l15,
//   holds w[co=mt*16+l15][k=kt*32+quad*8+j]  -> wave A-load = contiguous 1KB.
__device__ __align__(16) unsigned short g_wA[NKT_ * 8 * 64 * 8];
// col pixel-tile-blocked pair-interleaved: [b][pt(16pix)][pair][pl16] uints
//   {lo=ck even, hi=ck odd} -> a gemm block's slab is contiguous 36.9KB.
__device__ __align__(16) unsigned int   g_colu[(size_t)B_ * 256 * NPAIR_ * 16];
__device__ __align__(16) int4           g_desc[B_ * DG_ * K_ * HW_];   // {padded base, h2(w00,w01), h2(w10,w11), 0}

__device__ __forceinline__ unsigned short f32_to_bf16(float f) {
    unsigned int u = __float_as_uint(f);
    u += 0x7FFFu + ((u >> 16) & 1u);           // round-to-nearest-even
    return (unsigned short)(u >> 16);
}
__device__ __forceinline__ unsigned int pack_bf16x2(float a, float b) {
    return (unsigned int)f32_to_bf16(a) | ((unsigned int)f32_to_bf16(b) << 16);
}

// ---- Kernel 1: weight -> bf16 A-fragment layout  +  bilinear descriptors ----
__global__ __launch_bounds__(256) void prep_kernel(
    const float* __restrict__ w,
    const float* __restrict__ offset,
    const float* __restrict__ mask)
{
    const int bid = blockIdx.x;
    if (bid < 576) {
        // weights: 147456 elements into fragment order
        const int lin  = bid * 256 + threadIdx.x;
        const int j    = lin & 7;
        const int lane = (lin >> 3) & 63;
        const int mtkt = lin >> 9;             // kt*8 + mt
        const int mt   = mtkt & 7;
        const int kt   = mtkt >> 3;
        const int co   = mt * 16 + (lane & 15);
        const int k    = kt * 32 + (lane >> 4) * 8 + j;
        g_wA[lin] = f32_to_bf16(w[co * CK_ + k]);
    } else {
        // descriptors: 294912 = 72 bgk * 4096 pix
        const int lin = (bid - 576) * 256 + threadIdx.x;
        const int pix = lin & (HW_ - 1);
        const int bgk = lin >> 12;             // (b*2+g)*9 + k
        const int k   = bgk % 9;
        const int bg  = bgk / 9;
        const int ho = pix >> 6;
        const int wo = pix & 63;
        const int ky = k / 3;
        const int kx = k - 3 * ky;

        const float py = offset[(size_t)(bg * 18 + 2 * k)     * HW_ + pix] + (float)(ho - 1 + ky);
        const float px = offset[(size_t)(bg * 18 + 2 * k + 1) * HW_ + pix] + (float)(wo - 1 + kx);
        const float m  = mask  [(size_t)(bg * 9 + k)          * HW_ + pix];

        const float y0f = floorf(py);
        const float x0f = floorf(px);
        const float ly = py - y0f;
        const float lx = px - x0f;
        const int y0 = (int)y0f;
        const int x0 = (int)x0f;

        // clamped 2x2 load window + folded edge weights
        const bool yin = (y0 >= 0) & (y0 <= H_ - 2);
        const float er0 = yin ? (1.0f - ly) : ((y0 == -1)     ? ly          : 0.0f);
        const float er1 = yin ? ly          : ((y0 == H_ - 1) ? (1.0f - ly) : 0.0f);
        const bool xin = (x0 >= 0) & (x0 <= W_ - 2);
        const float ec0 = xin ? (1.0f - lx) : ((x0 == -1)     ? lx          : 0.0f);
        const float ec1 = xin ? lx          : ((x0 == W_ - 1) ? (1.0f - lx) : 0.0f);
        const int yc = min(max(y0, 0), H_ - 2);
        const int xc = min(max(x0, 0), W_ - 2);

        const __half2 wlo = __floats2half2_rn(m * er0 * ec0, m * er0 * ec1);
        const __half2 whi = __floats2half2_rn(m * er1 * ec0, m * er1 * ec1);
        int4 d;
        d.x = yc * PSTR_ + xc;                 // PADDED-plane base for LDS sampling
        d.y = __builtin_bit_cast(int, wlo);
        d.z = __builtin_bit_cast(int, whi);
        d.w = 0;
        g_desc[lin] = d;
    }
}

// ---- Kernel 2: col from LDS-staged planes. Block = (b, channel-pair). ----
// 256 blocks x 1024 threads. Whole 2 planes in LDS (padded rows); every
// bilinear tap = ds_read2_b32; clamped bases always in-plane.
__global__ __launch_bounds__(1024, 4) void col_kernel(const float* __restrict__ x)
{
    const int bid = blockIdx.x;            // 256 = 4b * 64 channel-pairs
    const int b   = bid >> 6;
    const int cp  = bid & 63;
    const int c0  = cp * 2;
    const int g   = c0 >> 6;
    const int t   = threadIdx.x;

    __shared__ __align__(16) float s_x[2 * PLSZ_];   // 34816 B

    {   // stage 2 planes, padded rows (8 floats per thread)
        const int ci = t >> 9;
        const int q  = t & 511;
        const float* __restrict__ src = x + (size_t)(b * C_ + c0 + ci) * HW_ + q * 8;
        const float4 v0 = *(const float4*)src;
        const float4 v1 = *(const float4*)(src + 4);
        float* dst = s_x + ci * PLSZ_ + (q >> 3) * PSTR_ + (q & 7) * 8;
        *(float4*)dst = v0;
        *(float4*)(dst + 4) = v1;
    }
    __syncthreads();

    const int4* __restrict__ descb = g_desc + (size_t)((b * DG_ + g) * 9) * HW_;

#pragma unroll
    for (int ps = 0; ps < 4; ++ps) {
        const int pix = ps * 1024 + t;
        const int pt  = pix >> 4;
        const int pl  = pix & 15;
        int4 d[9];
#pragma unroll
        for (int k = 0; k < 9; ++k) d[k] = descb[(size_t)k * HW_ + pix];

        float v[18];
#pragma unroll
        for (int k = 0; k < 9; ++k) {
            const float2 wl = __half22float2(__builtin_bit_cast(__half2, d[k].y));
            const float2 wh = __half22float2(__builtin_bit_cast(__half2, d[k].z));
#pragma unroll
            for (int ci = 0; ci < 2; ++ci) {
                const float* p = s_x + ci * PLSZ_ + d[k].x;
                const f2v lo = *(const f2v*)p;
                const f2v hi = *(const f2v*)(p + PSTR_);
                v[ci * 9 + k] = wl.x * lo.x + wl.y * lo.y + wh.x * hi.x + wh.y * hi.y;
            }
        }
        // local ck = ci*9+k -> pair j = cp*9 + jloc, dword {even ck, odd ck}
        unsigned int* __restrict__ outb =
            g_colu + ((size_t)(b * 256 + pt) * NPAIR_ + cp * 9) * 16 + pl;
#pragma unroll
        for (int j = 0; j < 9; ++j)
            outb[j * 16] = pack_bf16x2(v[2 * j], v[2 * j + 1]);
    }
}

// ---- Kernel 3: GEMM. 1024 blocks x 256 thr (4 waves), 4 blocks/CU. ----
// B-slab: contiguous 36.9KB global -> LDS transpose [pl][pair] (stride 580).
// B-frag = one ds_read_b128; A-frag = one contiguous-1KB dwordx4 from g_wA.
__global__ __launch_bounds__(256, 4) void gemm_kernel(
    const float* __restrict__ bias, float* __restrict__ out)
{
    const int bid  = blockIdx.x;           // 1024 = 4b * 256 ptiles(16)
    const int b    = bid >> 8;
    const int pt   = bid & 255;
    const int t    = threadIdx.x;

    __shared__ __align__(16) unsigned int s_b[16 * LSTR_];   // 37120 B

    {   // stage: 9 coalesced uint4 per thread, scatter-transpose into LDS
        const uint4* __restrict__ src =
            (const uint4*)(g_colu + (size_t)(b * 256 + pt) * (NPAIR_ * 16));
#pragma unroll
        for (int i = 0; i < 9; ++i) {
            const int c = i * 256 + t;         // 0..2303 chunk id
            const uint4 v = src[c];
            const int pair = c >> 2;
            const int plc  = (c & 3) * 4;
            s_b[(plc + 0) * LSTR_ + pair] = v.x;
            s_b[(plc + 1) * LSTR_ + pair] = v.y;
            s_b[(plc + 2) * LSTR_ + pair] = v.z;
            s_b[(plc + 3) * LSTR_ + pair] = v.w;
        }
    }
    __syncthreads();

    const int wv   = t >> 6;               // wave -> co 32-range
    const int lane = t & 63;
    const int l15  = lane & 15;
    const int quad = lane >> 4;

    // A: frag (kt, mt) at ((kt*8+mt)*64 + lane)*8; wave uses mt = 2wv, 2wv+1
    const unsigned short* __restrict__ ap =
        g_wA + ((size_t)(wv * 2) * 64 + lane) * 8;
    // B: frag (kt) at s_b[l15][kt*16 + quad*4 .. +3]
    const unsigned int* bp = s_b + l15 * LSTR_ + quad * 4;

    floatx4 acc0 = {0.f, 0.f, 0.f, 0.f};
    floatx4 acc1 = {0.f, 0.f, 0.f, 0.f};

    short8 a0c = *(const short8*)ap;
    short8 a1c = *(const short8*)(ap + 512);
    short8 b_c = __builtin_bit_cast(short8, *(const uint4*)bp);

#pragma unroll 4
    for (int kt = 0; kt < NKT_; ++kt) {
        short8 a0n = a0c, a1n = a1c, b_n = b_c;
        if (kt < NKT_ - 1) {
            const unsigned short* an = ap + (size_t)(kt + 1) * 4096;
            a0n = *(const short8*)an;
            a1n = *(const short8*)(an + 512);
            b_n = __builtin_bit_cast(short8, *(const uint4*)(bp + (kt + 1) * 16));
        }
        acc0 = __builtin_amdgcn_mfma_f32_16x16x32_bf16(a0c, b_c, acc0, 0, 0, 0);
        acc1 = __builtin_amdgcn_mfma_f32_16x16x32_bf16(a1c, b_c, acc1, 0, 0, 0);
        a0c = a0n; a1c = a1n; b_c = b_n;
    }

    // C/D: col = l15 (pixel), row = quad*4 + r (co within 16-tile)
#pragma unroll
    for (int mt = 0; mt < 2; ++mt) {
        const floatx4 a = mt ? acc1 : acc0;
        const int cob = wv * 32 + mt * 16 + quad * 4;
#pragma unroll
        for (int r = 0; r < 4; ++r) {
            const int co = cob + r;
            out[((size_t)(b * CO_ + co) << 12) + pt * 16 + l15] = a[r] + bias[co];
        }
    }
}

extern "C" void kernel_launch(void* const* d_in, const int* in_sizes, int n_in,
                              void* d_out, int out_size, void* d_ws, size_t ws_size,
                              hipStream_t stream) {
    const float* x      = (const float*)d_in[0];
    const float* offset = (const float*)d_in[1];
    const float* mask   = (const float*)d_in[2];
    const float* weight = (const float*)d_in[3];
    const float* bias   = (const float*)d_in[4];
    float* out = (float*)d_out;

    hipLaunchKernelGGL(prep_kernel, dim3(576 + 1152), dim3(256), 0, stream, weight, offset, mask);
    hipLaunchKernelGGL(col_kernel, dim3(B_ * 64), dim3(1024), 0, stream, x);
    hipLaunchKernelGGL(gemm_kernel, dim3(B_ * 256), dim3(256), 0, stream, bias, out);
}

// Round 7
// 102.613 us; speedup vs baseline: 2.9828x; 1.0429x over previous
//
#include <hip/hip_runtime.h>
#include <hip/hip_fp16.h>

// Problem constants (fixed by reference setup_inputs)
#define B_    4
#define C_    128
#define H_    64
#define W_    64
#define CO_   128
#define K_    9
#define DG_   2
#define HW_   4096
#define CK_   1152
#define NKT_  36        // CK_/32
#define NPAIR_ 576      // CK_/2
#define PSTR_ 68        // padded LDS plane row stride (floats) in col kernel
#define PLSZ_ 4352      // 64*PSTR_ floats per plane

typedef __attribute__((ext_vector_type(8))) short  short8;
typedef __attribute__((ext_vector_type(4))) float  floatx4;
typedef float f2v __attribute__((ext_vector_type(2), aligned(4)));   // dword-aligned pair

// Static staging buffers, fully rewritten every launch.
// A in MFMA-fragment order: [kt][mt(co16)][lane][8k], lane=quad*16+l15,
//   holds w[co=mt*16+l15][k=kt*32+quad*8+j]  -> wave A-load = contiguous 1KB.
__device__ __align__(16) unsigned short g_wA[NKT_ * 8 * 64 * 8];
// col 32-pixel-tile-blocked pair-interleaved: [b][pt32][pair][pl32] uints
//   {lo=ck even, hi=ck odd} -> a gemm block's slab is contiguous 73.7KB.
__device__ __align__(16) unsigned int   g_colu[(size_t)B_ * 128 * NPAIR_ * 32];
__device__ __align__(16) int4           g_desc[B_ * DG_ * K_ * HW_];   // {padded base, h2(w00,w01), h2(w10,w11), 0}

__device__ __forceinline__ unsigned short f32_to_bf16(float f) {
    unsigned int u = __float_as_uint(f);
    u += 0x7FFFu + ((u >> 16) & 1u);           // round-to-nearest-even
    return (unsigned short)(u >> 16);
}
__device__ __forceinline__ unsigned int pack_bf16x2(float a, float b) {
    return (unsigned int)f32_to_bf16(a) | ((unsigned int)f32_to_bf16(b) << 16);
}

// ---- Kernel 1: weight -> bf16 A-fragment layout  +  bilinear descriptors ----
__global__ __launch_bounds__(256) void prep_kernel(
    const float* __restrict__ w,
    const float* __restrict__ offset,
    const float* __restrict__ mask)
{
    const int bid = blockIdx.x;
    if (bid < 576) {
        // weights: 147456 elements into fragment order
        const int lin  = bid * 256 + threadIdx.x;
        const int j    = lin & 7;
        const int lane = (lin >> 3) & 63;
        const int mtkt = lin >> 9;             // kt*8 + mt
        const int mt   = mtkt & 7;
        const int kt   = mtkt >> 3;
        const int co   = mt * 16 + (lane & 15);
        const int k    = kt * 32 + (lane >> 4) * 8 + j;
        g_wA[lin] = f32_to_bf16(w[co * CK_ + k]);
    } else {
        // descriptors: 294912 = 72 bgk * 4096 pix
        const int lin = (bid - 576) * 256 + threadIdx.x;
        const int pix = lin & (HW_ - 1);
        const int bgk = lin >> 12;             // (b*2+g)*9 + k
        const int k   = bgk % 9;
        const int bg  = bgk / 9;
        const int ho = pix >> 6;
        const int wo = pix & 63;
        const int ky = k / 3;
        const int kx = k - 3 * ky;

        const float py = offset[(size_t)(bg * 18 + 2 * k)     * HW_ + pix] + (float)(ho - 1 + ky);
        const float px = offset[(size_t)(bg * 18 + 2 * k + 1) * HW_ + pix] + (float)(wo - 1 + kx);
        const float m  = mask  [(size_t)(bg * 9 + k)          * HW_ + pix];

        const float y0f = floorf(py);
        const float x0f = floorf(px);
        const float ly = py - y0f;
        const float lx = px - x0f;
        const int y0 = (int)y0f;
        const int x0 = (int)x0f;

        // clamped 2x2 load window + folded edge weights
        const bool yin = (y0 >= 0) & (y0 <= H_ - 2);
        const float er0 = yin ? (1.0f - ly) : ((y0 == -1)     ? ly          : 0.0f);
        const float er1 = yin ? ly          : ((y0 == H_ - 1) ? (1.0f - ly) : 0.0f);
        const bool xin = (x0 >= 0) & (x0 <= W_ - 2);
        const float ec0 = xin ? (1.0f - lx) : ((x0 == -1)     ? lx          : 0.0f);
        const float ec1 = xin ? lx          : ((x0 == W_ - 1) ? (1.0f - lx) : 0.0f);
        const int yc = min(max(y0, 0), H_ - 2);
        const int xc = min(max(x0, 0), W_ - 2);

        const __half2 wlo = __floats2half2_rn(m * er0 * ec0, m * er0 * ec1);
        const __half2 whi = __floats2half2_rn(m * er1 * ec0, m * er1 * ec1);
        int4 d;
        d.x = yc * PSTR_ + xc;                 // PADDED-plane base for LDS sampling
        d.y = __builtin_bit_cast(int, wlo);
        d.z = __builtin_bit_cast(int, whi);
        d.w = 0;
        g_desc[lin] = d;
    }
}

// ---- Kernel 2: col from LDS-staged planes. Block = (b, channel-pair). ----
// 256 blocks x 1024 threads. Whole 2 planes in LDS (padded rows); every
// bilinear tap = ds_read_b64; clamped bases always in-plane.
__global__ __launch_bounds__(1024, 4) void col_kernel(const float* __restrict__ x)
{
    const int bid = blockIdx.x;            // 256 = 4b * 64 channel-pairs
    const int b   = bid >> 6;
    const int cp  = bid & 63;
    const int c0  = cp * 2;
    const int g   = c0 >> 6;
    const int t   = threadIdx.x;

    __shared__ __align__(16) float s_x[2 * PLSZ_];   // 34816 B

    {   // stage 2 planes, padded rows (8 floats per thread)
        const int ci = t >> 9;
        const int q  = t & 511;
        const float* __restrict__ src = x + (size_t)(b * C_ + c0 + ci) * HW_ + q * 8;
        const float4 v0 = *(const float4*)src;
        const float4 v1 = *(const float4*)(src + 4);
        float* dst = s_x + ci * PLSZ_ + (q >> 3) * PSTR_ + (q & 7) * 8;
        *(float4*)dst = v0;
        *(float4*)(dst + 4) = v1;
    }
    __syncthreads();

    const int4* __restrict__ descb = g_desc + (size_t)((b * DG_ + g) * 9) * HW_;

#pragma unroll
    for (int ps = 0; ps < 4; ++ps) {
        const int pix = ps * 1024 + t;
        const int pt  = pix >> 5;
        const int pl  = pix & 31;
        int4 d[9];
#pragma unroll
        for (int k = 0; k < 9; ++k) d[k] = descb[(size_t)k * HW_ + pix];

        float v[18];
#pragma unroll
        for (int k = 0; k < 9; ++k) {
            const float2 wl = __half22float2(__builtin_bit_cast(__half2, d[k].y));
            const float2 wh = __half22float2(__builtin_bit_cast(__half2, d[k].z));
#pragma unroll
            for (int ci = 0; ci < 2; ++ci) {
                const float* p = s_x + ci * PLSZ_ + d[k].x;
                const f2v lo = *(const f2v*)p;
                const f2v hi = *(const f2v*)(p + PSTR_);
                v[ci * 9 + k] = wl.x * lo.x + wl.y * lo.y + wh.x * hi.x + wh.y * hi.y;
            }
        }
        // local ck = ci*9+k -> global pair = cp*9 + j, dword {even ck, odd ck}
        unsigned int* __restrict__ outb =
            g_colu + ((size_t)(b * 128 + pt) * NPAIR_ + cp * 9) * 32 + pl;
#pragma unroll
        for (int j = 0; j < 9; ++j)
            outb[j * 32] = pack_bf16x2(v[2 * j], v[2 * j + 1]);
    }
}

// ---- Kernel 3: GEMM, zero LDS, zero barriers. 512 blocks x 512 thr. ----
// 8 waves = 4 co-ranges x 2 pixel-subtiles over a 32-pixel slab.
// A-frag = contiguous 1KB/wave b128 from g_wA; B-frag = 4 coalesced b32
// (256B segments) from the contiguous 73.7KB col slab. Depth-1 prefetch.
__global__ __launch_bounds__(512) void gemm_kernel(
    const float* __restrict__ bias, float* __restrict__ out)
{
    const int bid  = blockIdx.x;           // 512 = 4b * 128 pt32
    const int b    = bid >> 7;
    const int pt   = bid & 127;
    const int t    = threadIdx.x;
    const int w    = t >> 6;               // wave 0..7
    const int cw   = w >> 1;               // co-range (32 co)
    const int nt   = w & 1;                // 16-pixel subtile
    const int lane = t & 63;
    const int l15  = lane & 15;
    const int quad = lane >> 4;

    // A: frag (kt, mt=cw*2+mtl) at ((kt*8+mt)*64 + lane)*8
    const unsigned short* __restrict__ ap = g_wA + ((size_t)(cw * 2) * 64 + lane) * 8;
    // B: lane reads pairs (kt*16 + quad*4 + j2) at pixel nt*16+l15
    const unsigned int* __restrict__ bp =
        g_colu + ((size_t)(b * 128 + pt) * NPAIR_ + quad * 4) * 32 + nt * 16 + l15;

    floatx4 acc0 = {0.f, 0.f, 0.f, 0.f};
    floatx4 acc1 = {0.f, 0.f, 0.f, 0.f};

    short8 a0c = *(const short8*)ap;
    short8 a1c = *(const short8*)(ap + 512);
    uint4 u0;
    u0.x = bp[0]; u0.y = bp[32]; u0.z = bp[64]; u0.w = bp[96];
    short8 b_c = __builtin_bit_cast(short8, u0);

#pragma unroll 4
    for (int kt = 0; kt < NKT_; ++kt) {
        short8 a0n = a0c, a1n = a1c, b_n = b_c;
        if (kt < NKT_ - 1) {
            const unsigned short* an = ap + (size_t)(kt + 1) * 4096;
            a0n = *(const short8*)an;
            a1n = *(const short8*)(an + 512);
            const unsigned int* bq = bp + (size_t)(kt + 1) * 512;
            uint4 u;
            u.x = bq[0]; u.y = bq[32]; u.z = bq[64]; u.w = bq[96];
            b_n = __builtin_bit_cast(short8, u);
        }
        acc0 = __builtin_amdgcn_mfma_f32_16x16x32_bf16(a0c, b_c, acc0, 0, 0, 0);
        acc1 = __builtin_amdgcn_mfma_f32_16x16x32_bf16(a1c, b_c, acc1, 0, 0, 0);
        a0c = a0n; a1c = a1n; b_c = b_n;
    }

    // C/D: col = l15 (pixel), row = quad*4 + r (co within 16-tile)
#pragma unroll
    for (int mtl = 0; mtl < 2; ++mtl) {
        const floatx4 a = mtl ? acc1 : acc0;
        const int cob = cw * 32 + mtl * 16 + quad * 4;
#pragma unroll
        for (int r = 0; r < 4; ++r) {
            const int co = cob + r;
            out[((size_t)(b * CO_ + co) << 12) + pt * 32 + nt * 16 + l15] = a[r] + bias[co];
        }
    }
}

extern "C" void kernel_launch(void* const* d_in, const int* in_sizes, int n_in,
                              void* d_out, int out_size, void* d_ws, size_t ws_size,
                              hipStream_t stream) {
    const float* x      = (const float*)d_in[0];
    const float* offset = (const float*)d_in[1];
    const float* mask   = (const float*)d_in[2];
    const float* weight = (const float*)d_in[3];
    const float* bias   = (const float*)d_in[4];
    float* out = (float*)d_out;

    hipLaunchKernelGGL(prep_kernel, dim3(576 + 1152), dim3(256), 0, stream, weight, offset, mask);
    hipLaunchKernelGGL(col_kernel, dim3(B_ * 64), dim3(1024), 0, stream, x);
    hipLaunchKernelGGL(gemm_kernel, dim3(B_ * 128), dim3(512), 0, stream, bias, out);
}

// Round 8
// 100.324 us; speedup vs baseline: 3.0508x; 1.0228x over previous
//
#include <hip/hip_runtime.h>
#include <hip/hip_fp16.h>

// Problem constants (fixed by reference setup_inputs)
#define B_    4
#define C_    128
#define H_    64
#define W_    64
#define CO_   128
#define K_    9
#define DG_   2
#define HW_   4096
#define CK_   1152
#define NKT_  36        // CK_/32
#define NPAIR_ 576      // CK_/2
#define XSTR_ 68        // LDS plane row stride in h4v elements (8B): bank-rotating

typedef __attribute__((ext_vector_type(8))) short    short8;
typedef __attribute__((ext_vector_type(4))) float    floatx4;
typedef __attribute__((ext_vector_type(4))) _Float16 h4v;    // 8B, one pixel x 4 channels

// Static staging buffers, fully rewritten every launch.
// K-dimension is reordered k-major: ck' = k*128 + c (A and B agree; GEMM is
// order-invariant). A in MFMA-fragment order: [kt][mt(co16)][lane][8k'].
__device__ __align__(16) unsigned short g_wA[NKT_ * 8 * 64 * 8];
// col 64-pixel-tile-blocked pair-interleaved: [b][pt64][pair'][pl64] uints,
// pair' = k*64 + c/2, dword = {bf16 ck'=2p, bf16 ck'=2p+1} (channels 2c,2c+1).
__device__ __align__(16) unsigned int   g_colu[(size_t)B_ * 64 * NPAIR_ * 64];
__device__ __align__(16) int4           g_desc[B_ * DG_ * K_ * HW_];   // {padded base, h2(w00,w01), h2(w10,w11), 0}

__device__ __forceinline__ unsigned short f32_to_bf16(float f) {
    unsigned int u = __float_as_uint(f);
    u += 0x7FFFu + ((u >> 16) & 1u);           // round-to-nearest-even
    return (unsigned short)(u >> 16);
}
__device__ __forceinline__ unsigned int pack_bf16x2(float a, float b) {
    return (unsigned int)f32_to_bf16(a) | ((unsigned int)f32_to_bf16(b) << 16);
}

// ---- Kernel 1: weight -> bf16 A-fragment layout (k-major) + descriptors ----
__global__ __launch_bounds__(256) void prep_kernel(
    const float* __restrict__ w,
    const float* __restrict__ offset,
    const float* __restrict__ mask)
{
    const int bid = blockIdx.x;
    if (bid < 576) {
        // weights: 147456 elements into fragment order, k-major ck'
        const int lin  = bid * 256 + threadIdx.x;
        const int j    = lin & 7;
        const int lane = (lin >> 3) & 63;
        const int mtkt = lin >> 9;             // kt*8 + mt
        const int mt   = mtkt & 7;
        const int kt   = mtkt >> 3;
        const int co   = mt * 16 + (lane & 15);
        const int kp   = kt * 32 + (lane >> 4) * 8 + j;   // ck' = k*128 + c
        const int c    = kp & 127;
        const int k    = kp >> 7;
        g_wA[lin] = f32_to_bf16(w[co * CK_ + c * 9 + k]);
    } else {
        // descriptors: 294912 = 72 bgk * 4096 pix
        const int lin = (bid - 576) * 256 + threadIdx.x;
        const int pix = lin & (HW_ - 1);
        const int bgk = lin >> 12;             // (b*2+g)*9 + k
        const int k   = bgk % 9;
        const int bg  = bgk / 9;
        const int ho = pix >> 6;
        const int wo = pix & 63;
        const int ky = k / 3;
        const int kx = k - 3 * ky;

        const float py = offset[(size_t)(bg * 18 + 2 * k)     * HW_ + pix] + (float)(ho - 1 + ky);
        const float px = offset[(size_t)(bg * 18 + 2 * k + 1) * HW_ + pix] + (float)(wo - 1 + kx);
        const float m  = mask  [(size_t)(bg * 9 + k)          * HW_ + pix];

        const float y0f = floorf(py);
        const float x0f = floorf(px);
        const float ly = py - y0f;
        const float lx = px - x0f;
        const int y0 = (int)y0f;
        const int x0 = (int)x0f;

        // clamped 2x2 load window + folded edge weights
        const bool yin = (y0 >= 0) & (y0 <= H_ - 2);
        const float er0 = yin ? (1.0f - ly) : ((y0 == -1)     ? ly          : 0.0f);
        const float er1 = yin ? ly          : ((y0 == H_ - 1) ? (1.0f - ly) : 0.0f);
        const bool xin = (x0 >= 0) & (x0 <= W_ - 2);
        const float ec0 = xin ? (1.0f - lx) : ((x0 == -1)     ? lx          : 0.0f);
        const float ec1 = xin ? lx          : ((x0 == W_ - 1) ? (1.0f - lx) : 0.0f);
        const int yc = min(max(y0, 0), H_ - 2);
        const int xc = min(max(x0, 0), W_ - 2);

        const __half2 wlo = __floats2half2_rn(m * er0 * ec0, m * er0 * ec1);
        const __half2 whi = __floats2half2_rn(m * er1 * ec0, m * er1 * ec1);
        int4 d;
        d.x = yc * XSTR_ + xc;                 // padded-plane ELEMENT base
        d.y = __builtin_bit_cast(int, wlo);
        d.z = __builtin_bit_cast(int, whi);
        d.w = 0;
        g_desc[lin] = d;
    }
}

// ---- Kernel 2 (hot): col from 4-channel-interleaved fp16 LDS planes. ----
// Block = (b, channel-quad, pixel-quarter): 512 blocks x 1024 thr.
// Tap-row read = ds_read2_b64 -> (x,x+1) x 4 channels; per-k compute+store
// (k-major pairs are channel-contiguous) keeps VGPR low -> 2 blocks/CU.
__global__ __launch_bounds__(1024) void col_kernel(const float* __restrict__ x)
{
    const int bid = blockIdx.x;            // 512 = 4b * 32cq * 4qu
    const int b   = bid >> 7;
    const int rem = bid & 127;
    const int cq  = rem >> 2;              // channel quad 0..31
    const int qu  = rem & 3;
    const int c0  = cq * 4;
    const int g   = cq >> 4;               // deform group
    const int t   = threadIdx.x;

    __shared__ h4v s_x4[64 * XSTR_];       // 34816 B

    {   // stage 4 planes interleaved: thread t -> pixels 4t..4t+3
        const int p0  = t * 4;
        const int row = p0 >> 6;
        const int col = p0 & 63;
        const float* __restrict__ src = x + ((size_t)(b * C_ + c0) << 12) + p0;
        const float4 f0 = *(const float4*)(src);
        const float4 f1 = *(const float4*)(src + HW_);
        const float4 f2 = *(const float4*)(src + 2 * HW_);
        const float4 f3 = *(const float4*)(src + 3 * HW_);
        h4v* dst = s_x4 + row * XSTR_ + col;
        dst[0] = h4v{(_Float16)f0.x, (_Float16)f1.x, (_Float16)f2.x, (_Float16)f3.x};
        dst[1] = h4v{(_Float16)f0.y, (_Float16)f1.y, (_Float16)f2.y, (_Float16)f3.y};
        dst[2] = h4v{(_Float16)f0.z, (_Float16)f1.z, (_Float16)f2.z, (_Float16)f3.z};
        dst[3] = h4v{(_Float16)f0.w, (_Float16)f1.w, (_Float16)f2.w, (_Float16)f3.w};
    }
    __syncthreads();

    const int pix = qu * 1024 + t;
    const int pt  = pix >> 6;
    const int pl  = pix & 63;
    const int4* __restrict__ descb =
        g_desc + (size_t)((b * DG_ + g) * 9) * HW_ + pix;
    unsigned int* __restrict__ outb =
        g_colu + ((size_t)(b * 64 + pt) * NPAIR_ + 2 * cq) * 64 + pl;

#pragma unroll
    for (int k = 0; k < 9; ++k) {
        const int4 d = descb[(size_t)k * HW_];
        const float2 wl = __half22float2(__builtin_bit_cast(__half2, d.y));
        const float2 wh = __half22float2(__builtin_bit_cast(__half2, d.z));
        const h4v* p = s_x4 + d.x;
        const h4v lo0 = p[0];
        const h4v lo1 = p[1];
        const h4v hi0 = p[XSTR_];
        const h4v hi1 = p[XSTR_ + 1];
        float v[4];
#pragma unroll
        for (int ci = 0; ci < 4; ++ci)
            v[ci] = wl.x * (float)lo0[ci] + wl.y * (float)lo1[ci]
                  + wh.x * (float)hi0[ci] + wh.y * (float)hi1[ci];
        // pair' = k*64 + 2cq + {0,1}; dword = {even ck', odd ck'} = ch pairs
        outb[k * 64 * 64]      = pack_bf16x2(v[0], v[1]);
        outb[k * 64 * 64 + 64] = pack_bf16x2(v[2], v[3]);
    }
}

// ---- Kernel 3: GEMM, zero LDS, zero barriers. 256 blocks x 1024 thr. ----
// 16 waves = 4 co-ranges x 4 pixel-subtiles over a 64-pixel slab (147KB
// contiguous). A-frag = contiguous 1KB/wave b128 from g_wA (75MB total L2);
// B-frag = 4 coalesced b32. Depth-1 prefetch.
__global__ __launch_bounds__(1024) void gemm_kernel(
    const float* __restrict__ bias, float* __restrict__ out)
{
    const int bid  = blockIdx.x;           // 256 = 4b * 64 pt64
    const int b    = bid >> 6;
    const int pt   = bid & 63;
    const int t    = threadIdx.x;
    const int w    = t >> 6;               // wave 0..15
    const int cw   = w >> 2;               // co-range (32 co)
    const int nt   = w & 3;                // 16-pixel subtile
    const int lane = t & 63;
    const int l15  = lane & 15;
    const int quad = lane >> 4;

    // A: frag (kt, mt=cw*2+mtl) at ((kt*8+mt)*64 + lane)*8
    const unsigned short* __restrict__ ap = g_wA + ((size_t)(cw * 2) * 64 + lane) * 8;
    // B: lane reads pairs (kt*16 + quad*4 + j2) at pixel nt*16+l15
    const unsigned int* __restrict__ bp =
        g_colu + ((size_t)(b * 64 + pt) * NPAIR_ + quad * 4) * 64 + nt * 16 + l15;

    floatx4 acc0 = {0.f, 0.f, 0.f, 0.f};
    floatx4 acc1 = {0.f, 0.f, 0.f, 0.f};

    short8 a0c = *(const short8*)ap;
    short8 a1c = *(const short8*)(ap + 512);
    uint4 u0;
    u0.x = bp[0]; u0.y = bp[64]; u0.z = bp[128]; u0.w = bp[192];
    short8 b_c = __builtin_bit_cast(short8, u0);

#pragma unroll 4
    for (int kt = 0; kt < NKT_; ++kt) {
        short8 a0n = a0c, a1n = a1c, b_n = b_c;
        if (kt < NKT_ - 1) {
            const unsigned short* an = ap + (size_t)(kt + 1) * 4096;
            a0n = *(const short8*)an;
            a1n = *(const short8*)(an + 512);
            const unsigned int* bq = bp + (size_t)(kt + 1) * 1024;
            uint4 u;
            u.x = bq[0]; u.y = bq[64]; u.z = bq[128]; u.w = bq[192];
            b_n = __builtin_bit_cast(short8, u);
        }
        acc0 = __builtin_amdgcn_mfma_f32_16x16x32_bf16(a0c, b_c, acc0, 0, 0, 0);
        acc1 = __builtin_amdgcn_mfma_f32_16x16x32_bf16(a1c, b_c, acc1, 0, 0, 0);
        a0c = a0n; a1c = a1n; b_c = b_n;
    }

    // C/D: col = l15 (pixel), row = quad*4 + r (co within 16-tile)
    const int pixo = pt * 64 + nt * 16 + l15;
#pragma unroll
    for (int mtl = 0; mtl < 2; ++mtl) {
        const floatx4 a = mtl ? acc1 : acc0;
        const int cob = cw * 32 + mtl * 16 + quad * 4;
#pragma unroll
        for (int r = 0; r < 4; ++r) {
            const int co = cob + r;
            out[((size_t)(b * CO_ + co) << 12) + pixo] = a[r] + bias[co];
        }
    }
}

extern "C" void kernel_launch(void* const* d_in, const int* in_sizes, int n_in,
                              void* d_out, int out_size, void* d_ws, size_t ws_size,
                              hipStream_t stream) {
    const float* x      = (const float*)d_in[0];
    const float* offset = (const float*)d_in[1];
    const float* mask   = (const float*)d_in[2];
    const float* weight = (const float*)d_in[3];
    const float* bias   = (const float*)d_in[4];
    float* out = (float*)d_out;

    hipLaunchKernelGGL(prep_kernel, dim3(576 + 1152), dim3(256), 0, stream, weight, offset, mask);
    hipLaunchKernelGGL(col_kernel, dim3(512), dim3(1024), 0, stream, x);
    hipLaunchKernelGGL(gemm_kernel, dim3(256), dim3(1024), 0, stream, bias, out);
}